// Round 10
// baseline (2094.873 us; speedup 1.0000x reference)
//
#include <hip/hip_runtime.h>
#include <hip/hip_bf16.h>
#include <math.h>

#define T_STEPS 256
#define BATCH 64
#define DIN 256
#define DSTATE 512
#define NGATE 2048   // 4*DSTATE
#define NCLS 10000
#define NCLS_PAD 10112   // 79 * 128
#define ROWS 16384   // T_STEPS*BATCH
#define SCAN_BLOCKS 64
#define GROUP_BLOCKS 16  // blocks per batch-group (barrier scope)
#define CHUNK_ROWS 4096  // rows per logits/softmax chunk (bf16 path)
#define NSLOT 158        // dot partial slots per row (79 n-tiles x 2 waves)
#define NSLOT_PAD 160

typedef __attribute__((ext_vector_type(8))) short bf16x8;
typedef __attribute__((ext_vector_type(4))) float f32x4;

__device__ inline unsigned short f2b(float x) {
    __hip_bfloat16 h = __float2bfloat16(x);
    return *(unsigned short*)&h;
}
__device__ inline float b2f(unsigned short u) {
    return __uint_as_float(((unsigned int)u) << 16);
}

// ---- fused prep: all independent format conversions in ONE launch --------
// sections: [0,4096) inputs->bf16 | [4096,8192) WhT | [8192,10240) WxT |
// [10240,10248) bias | [10248,10280) h0->bf16 | [10280] bar | [10281,11545) WoT transpose
__launch_bounds__(256)
__global__ void prep_all(const float* __restrict__ inputs, const float* __restrict__ Wx,
                         const float* __restrict__ Wh, const float* __restrict__ bias,
                         const float* __restrict__ h0, const float* __restrict__ Wo,
                         unsigned short* __restrict__ Xb, unsigned short* __restrict__ WxT,
                         unsigned short* __restrict__ WhT, float* __restrict__ bp,
                         unsigned short* __restrict__ h0b, unsigned* __restrict__ bar,
                         unsigned short* __restrict__ WoT) {
    __shared__ float tile[64][65];
    const int bid = blockIdx.x;
    const int tid = threadIdx.x;
    if (bid < 4096) {                         // inputs -> bf16 (float4 quads)
        int i = bid * 256 + tid;
        float4 v = *(const float4*)&inputs[(size_t)i * 4];
        ushort4 o; o.x = f2b(v.x); o.y = f2b(v.y); o.z = f2b(v.z); o.w = f2b(v.w);
        *(ushort4*)&Xb[(size_t)i * 4] = o;
    } else if (bid < 8192) {                  // WhT: permute+transpose+cvt
        int e = (bid - 4096) * 256 + tid;
        int jp = e >> 9, k = e & 511;
        int s = jp >> 2, g = jp & 3;
        WhT[e] = f2b(Wh[(size_t)k * NGATE + g * DSTATE + s]);
    } else if (bid < 10240) {                 // WxT
        int e = (bid - 8192) * 256 + tid;
        int jp = e >> 8, k = e & 255;
        int s = jp >> 2, g = jp & 3;
        WxT[e] = f2b(Wx[(size_t)k * NGATE + g * DSTATE + s]);
    } else if (bid < 10248) {                 // bias permute
        int jp = (bid - 10240) * 256 + tid;
        bp[jp] = bias[(jp & 3) * DSTATE + (jp >> 2)];
    } else if (bid < 10280) {                 // h0 -> bf16
        int i = (bid - 10248) * 256 + tid;
        float4 v = *(const float4*)&h0[(size_t)i * 4];
        ushort4 o; o.x = f2b(v.x); o.y = f2b(v.y); o.z = f2b(v.z); o.w = f2b(v.w);
        *(ushort4*)&h0b[(size_t)i * 4] = o;
    } else if (bid < 10281) {                 // barrier words
        bar[tid] = 0u;
    } else {                                  // WoT tiled transpose + cvt
        int nb = bid - 10281;                 // 0..1263  (158 x 8)
        int n0 = (nb % 158) * 64, k0 = (nb / 158) * 64;
        #pragma unroll
        for (int r = 0; r < 16; ++r) {
            int k = (tid >> 6) + r * 4;
            int n = tid & 63;
            float v = (n0 + n < NCLS) ? Wo[(size_t)(k0 + k) * NCLS + n0 + n] : 0.f;
            tile[k][n] = v;
        }
        __syncthreads();
        #pragma unroll
        for (int r = 0; r < 16; ++r) {
            int n = (tid >> 6) + r * 4;
            int k = tid & 63;
            WoT[(size_t)(n0 + n) * DSTATE + k0 + k] = f2b(tile[k][n]);
        }
    }
}

// ---- Zx = X @ Wx (+bias), output transposed: ZxT[t][jp][b] bf16 ---------
__launch_bounds__(256)
__global__ void zx_gemm(const unsigned short* __restrict__ Xb,   // [16384][256]
                        const unsigned short* __restrict__ WxT,  // [2048][256]
                        const float* __restrict__ bp,            // [2048]
                        unsigned short* __restrict__ ZxT) {      // [256][2048][64]
    __shared__ unsigned short As[64][264];
    __shared__ unsigned short Bs[128][264];
    __shared__ float zls[4][32][65];
    const int tid = threadIdx.x;
    const int t = blockIdx.x;
    const int n0 = blockIdx.y * 128;
    const int wave = tid >> 6, lane = tid & 63, mr = lane & 15, g = lane >> 4;

    #pragma unroll
    for (int r = 0; r < 8; ++r) {
        int c = r * 256 + tid; int row = c >> 5, q = c & 31;
        *(int4*)&As[row][q * 8] = *(const int4*)&Xb[((size_t)t * 64 + row) * DIN + q * 8];
    }
    #pragma unroll
    for (int r = 0; r < 16; ++r) {
        int c = r * 256 + tid; int row = c >> 5, q = c & 31;
        *(int4*)&Bs[row][q * 8] = *(const int4*)&WxT[(size_t)(n0 + row) * DIN + q * 8];
    }
    __syncthreads();

    f32x4 acc[4][2] = {};
    #pragma unroll
    for (int kt = 0; kt < DIN; kt += 32) {
        bf16x8 af[4], bf[2];
        #pragma unroll
        for (int fm = 0; fm < 4; ++fm) af[fm] = *(const bf16x8*)&As[fm * 16 + mr][kt + g * 8];
        #pragma unroll
        for (int fn = 0; fn < 2; ++fn) bf[fn] = *(const bf16x8*)&Bs[wave * 32 + fn * 16 + mr][kt + g * 8];
        #pragma unroll
        for (int fm = 0; fm < 4; ++fm)
            #pragma unroll
            for (int fn = 0; fn < 2; ++fn)
                acc[fm][fn] = __builtin_amdgcn_mfma_f32_16x16x32_bf16(af[fm], bf[fn], acc[fm][fn], 0, 0, 0);
    }
    #pragma unroll
    for (int fm = 0; fm < 4; ++fm)
        #pragma unroll
        for (int fn = 0; fn < 2; ++fn)
            #pragma unroll
            for (int r = 0; r < 4; ++r)
                zls[wave][fn * 16 + mr][fm * 16 + g * 4 + r] = acc[fm][fn][r];
    #pragma unroll 4
    for (int jr = 0; jr < 32; ++jr) {
        int j = n0 + wave * 32 + jr;
        float v = zls[wave][jr][lane] + bp[j];
        ZxT[((size_t)t * NGATE + j) * 64 + lane] = f2b(v);
    }
}

// ---- agent-scope GROUP barrier (r4-proven structure, 16 participants) ----
__device__ __forceinline__ void groupbar(unsigned* cnt, unsigned* flg, unsigned want, int tid) {
    __syncthreads();   // drains vmcnt: all h-stores of this block are complete
    if (tid == 0) {
        unsigned old = __hip_atomic_fetch_add(cnt, 1u, __ATOMIC_ACQ_REL, __HIP_MEMORY_SCOPE_AGENT);
        if (old == GROUP_BLOCKS - 1) {
            __hip_atomic_store(cnt, 0u, __ATOMIC_RELAXED, __HIP_MEMORY_SCOPE_AGENT);
            __hip_atomic_store(flg, want, __ATOMIC_RELEASE, __HIP_MEMORY_SCOPE_AGENT);
        } else {
            while (__hip_atomic_load(flg, __ATOMIC_RELAXED, __HIP_MEMORY_SCOPE_AGENT) < want) {}
            (void)__hip_atomic_load(flg, __ATOMIC_ACQUIRE, __HIP_MEMORY_SCOPE_AGENT);
        }
    }
    __syncthreads();
}

// ---- cooperative LSTM scan, batch-grouped: 4 groups x 16 blocks (r9) -----
__launch_bounds__(256, 1)
__global__ void lstm_scan_mfma(const unsigned short* __restrict__ h0b,  // [64][512] bf16
                               const float* __restrict__ c0,            // [64][512] f32
                               const unsigned short* __restrict__ WhT,  // [2048][512] bf16
                               const unsigned short* __restrict__ ZxT,  // [256][2048][64] bf16
                               unsigned short* __restrict__ hsb,        // [256][64][512] bf16
                               unsigned* __restrict__ bar) {
    __shared__ unsigned short Wl[128][520];  // 133,120 B
    __shared__ unsigned short hT[16][520];   //  16,640 B
    __shared__ float zb[16][132];            //   8,448 B
    const int tid = threadIdx.x;
    const int bid = blockIdx.x;
    const int grp = bid >> 4;
    const int w   = bid & 15;
    const int b0  = grp * 16;
    const int j0  = w * 128;
    const int s0  = w * 32;
    const int wave = tid >> 6, lane = tid & 63, mr = lane & 15, gl = lane >> 4;
    unsigned* bcnt = bar + grp * 64;
    unsigned* bflg = bar + grp * 64 + 32;

    #pragma unroll 4
    for (int r = 0; r < 32; ++r) {
        int c = r * 256 + tid; int row = c >> 6, q = c & 63;
        *(int4*)&Wl[row][q * 8] = *(const int4*)&WhT[(size_t)(j0 + row) * DSTATE + q * 8];
    }

    const int gb  = lane >> 2;
    const int slg = wave * 8 + (lane & 3) * 2;
    float creg0 = c0[(b0 + gb) * DSTATE + s0 + slg];
    float creg1 = c0[(b0 + gb) * DSTATE + s0 + slg + 1];
    __syncthreads();

    const size_t zo0 = ((size_t)(j0 + wave * 32 + mr)) * 64 + b0 + gl * 4;
    const size_t zo1 = ((size_t)(j0 + wave * 32 + 16 + mr)) * 64 + b0 + gl * 4;
    ushort4 za0 = *(const ushort4*)&ZxT[zo0];
    ushort4 za1 = *(const ushort4*)&ZxT[zo1];

    for (int t = 0; t < T_STEPS; ++t) {
        const unsigned short* hsrc = t ? (hsb + (size_t)(t - 1) * BATCH * DSTATE) : h0b;
        #pragma unroll
        for (int r = 0; r < 4; ++r) {
            int c = r * 256 + tid; int row = c >> 6, q = c & 63;
            *(int4*)&hT[row][q * 8] = *(const int4*)&hsrc[(size_t)(b0 + row) * DSTATE + q * 8];
        }
        __syncthreads();

        f32x4 acc0, acc1;
        acc0[0] = b2f(za0.x); acc0[1] = b2f(za0.y); acc0[2] = b2f(za0.z); acc0[3] = b2f(za0.w);
        acc1[0] = b2f(za1.x); acc1[1] = b2f(za1.y); acc1[2] = b2f(za1.z); acc1[3] = b2f(za1.w);
        if (t + 1 < T_STEPS) {
            za0 = *(const ushort4*)&ZxT[(size_t)(t + 1) * NGATE * 64 + zo0];
            za1 = *(const ushort4*)&ZxT[(size_t)(t + 1) * NGATE * 64 + zo1];
        }
        #pragma unroll
        for (int kt = 0; kt < DSTATE; kt += 32) {
            bf16x8 af = *(const bf16x8*)&hT[mr][kt + gl * 8];
            acc0 = __builtin_amdgcn_mfma_f32_16x16x32_bf16(af, *(const bf16x8*)&Wl[wave * 32 + mr][kt + gl * 8], acc0, 0, 0, 0);
            acc1 = __builtin_amdgcn_mfma_f32_16x16x32_bf16(af, *(const bf16x8*)&Wl[wave * 32 + 16 + mr][kt + gl * 8], acc1, 0, 0, 0);
        }
        #pragma unroll
        for (int r = 0; r < 4; ++r) {
            zb[gl * 4 + r][wave * 32 + mr] = acc0[r];
            zb[gl * 4 + r][wave * 32 + 16 + mr] = acc1[r];
        }
        {
            float zi0 = zb[gb][slg * 4 + 0], zf0 = zb[gb][slg * 4 + 1];
            float zg0 = zb[gb][slg * 4 + 2], zo0v = zb[gb][slg * 4 + 3];
            float zi1 = zb[gb][slg * 4 + 4], zf1 = zb[gb][slg * 4 + 5];
            float zg1 = zb[gb][slg * 4 + 6], zo1v = zb[gb][slg * 4 + 7];
            float i0 = 1.f / (1.f + expf(-zi0)), f0 = 1.f / (1.f + expf(-zf0));
            float o0 = 1.f / (1.f + expf(-zo0v)), g0 = tanhf(zg0);
            float i1 = 1.f / (1.f + expf(-zi1)), f1 = 1.f / (1.f + expf(-zf1));
            float o1 = 1.f / (1.f + expf(-zo1v)), g1 = tanhf(zg1);
            creg0 = f0 * creg0 + i0 * g0;
            creg1 = f1 * creg1 + i1 * g1;
            float h0v = o0 * tanhf(creg0);
            float h1v = o1 * tanhf(creg1);
            ushort2 hv; hv.x = f2b(h0v); hv.y = f2b(h1v);
            *(ushort2*)&hsb[((size_t)t * BATCH + b0 + gb) * DSTATE + s0 + slg] = hv;
        }
        if (t != T_STEPS - 1)
            groupbar(bcnt, bflg, (unsigned)(t + 1), tid);
    }
}

// ---- logits GEMM, bf16 C + fused label-dot partials (chunked path) -------
// 1D grid 2528 blocks, XCD-bijective swizzle (2528 % 8 == 0).
__launch_bounds__(256)
__global__ void gemm_logits_bf16(const unsigned short* __restrict__ A,   // [chunk][512]
                                 const unsigned short* __restrict__ Bt,  // [NCLS_PAD][512]
                                 const float* __restrict__ bo,
                                 const float* __restrict__ labels,       // chunk base
                                 unsigned short* __restrict__ Cb,        // [chunk][NCLS]
                                 float* __restrict__ dotp) {             // [chunk][NSLOT_PAD]
    __shared__ unsigned short As[128 * 32];
    __shared__ unsigned short Bs[128 * 32];
    const int tid = threadIdx.x;
    const int wave = tid >> 6, lane = tid & 63;
    const int wm = wave >> 1, wn = wave & 1;
    const int id = blockIdx.x;
    const int swz = (id & 7) * 316 + (id >> 3);   // XCD-contiguous chunks
    const int m0 = (swz & 31) * 128;
    const int n0 = (swz >> 5) * 128;
    const int g = lane >> 4, mr = lane & 15;

    const int ch0 = wave * 64 + lane;
    const int ch1 = (4 + wave) * 64 + lane;
    const int row0 = ch0 >> 2, q0 = ch0 & 3;
    const int row1 = ch1 >> 2, q1 = ch1 & 3;

    f32x4 acc[4][4] = {};
    for (int kt = 0; kt < DSTATE; kt += 32) {
        __builtin_amdgcn_global_load_lds(
            (const __attribute__((address_space(1))) void*)&A[(size_t)(m0 + row0) * DSTATE + kt + q0 * 8],
            (__attribute__((address_space(3))) void*)&As[ch0 * 8 - lane * 8], 16, 0, 0);
        __builtin_amdgcn_global_load_lds(
            (const __attribute__((address_space(1))) void*)&A[(size_t)(m0 + row1) * DSTATE + kt + q1 * 8],
            (__attribute__((address_space(3))) void*)&As[ch1 * 8 - lane * 8], 16, 0, 0);
        __builtin_amdgcn_global_load_lds(
            (const __attribute__((address_space(1))) void*)&Bt[(size_t)(n0 + row0) * DSTATE + kt + q0 * 8],
            (__attribute__((address_space(3))) void*)&Bs[ch0 * 8 - lane * 8], 16, 0, 0);
        __builtin_amdgcn_global_load_lds(
            (const __attribute__((address_space(1))) void*)&Bt[(size_t)(n0 + row1) * DSTATE + kt + q1 * 8],
            (__attribute__((address_space(3))) void*)&Bs[ch1 * 8 - lane * 8], 16, 0, 0);
        __syncthreads();

        bf16x8 af[4], bf[4];
        #pragma unroll
        for (int f = 0; f < 4; ++f) {
            af[f] = *(const bf16x8*)&As[(wm * 64 + f * 16 + mr) * 32 + g * 8];
            bf[f] = *(const bf16x8*)&Bs[(wn * 64 + f * 16 + mr) * 32 + g * 8];
        }
        #pragma unroll
        for (int fm = 0; fm < 4; ++fm)
            #pragma unroll
            for (int fn = 0; fn < 4; ++fn)
                acc[fm][fn] = __builtin_amdgcn_mfma_f32_16x16x32_bf16(af[fm], bf[fn], acc[fm][fn], 0, 0, 0);
        __syncthreads();
    }
    // epilogue: bf16 store + per-row label-dot partial over this wave's 64 cols
    #pragma unroll
    for (int fm = 0; fm < 4; ++fm) {
        float dots[4] = {0.f, 0.f, 0.f, 0.f};
        #pragma unroll
        for (int fn = 0; fn < 4; ++fn) {
            int col = n0 + wn * 64 + fn * 16 + mr;
            if (col < NCLS) {
                float bias = bo[col];
                #pragma unroll
                for (int r = 0; r < 4; ++r) {
                    int row = m0 + wm * 64 + fm * 16 + g * 4 + r;
                    float lg = acc[fm][fn][r] + bias;
                    Cb[(size_t)row * NCLS + col] = f2b(lg);
                    dots[r] += labels[(size_t)row * NCLS + col] * lg;
                }
            }
        }
        #pragma unroll
        for (int r = 0; r < 4; ++r) {
            float d = dots[r];
            d += __shfl_xor(d, 1); d += __shfl_xor(d, 2);
            d += __shfl_xor(d, 4); d += __shfl_xor(d, 8);
            if (mr == 0) {
                int row = m0 + wm * 64 + fm * 16 + g * 4 + r;
                dotp[(size_t)row * NSLOT_PAD + (swz >> 5) * 2 + wn] = d;
            }
        }
    }
}

// ---- logits GEMM, f32 C (fallback path) ----------------------------------
__launch_bounds__(256)
__global__ void gemm_logits_mfma(const unsigned short* __restrict__ A,
                                 const unsigned short* __restrict__ Bt,
                                 const float* __restrict__ bo,
                                 float* __restrict__ C) {
    __shared__ unsigned short As[128 * 32];
    __shared__ unsigned short Bs[128 * 32];
    const int tid = threadIdx.x;
    const int wave = tid >> 6, lane = tid & 63;
    const int wm = wave >> 1, wn = wave & 1;
    const int m0 = blockIdx.y * 128, n0 = blockIdx.x * 128;
    const int g = lane >> 4, mr = lane & 15;

    const int ch0 = wave * 64 + lane;
    const int ch1 = (4 + wave) * 64 + lane;
    const int row0 = ch0 >> 2, q0 = ch0 & 3;
    const int row1 = ch1 >> 2, q1 = ch1 & 3;

    f32x4 acc[4][4] = {};
    for (int kt = 0; kt < DSTATE; kt += 32) {
        __builtin_amdgcn_global_load_lds(
            (const __attribute__((address_space(1))) void*)&A[(size_t)(m0 + row0) * DSTATE + kt + q0 * 8],
            (__attribute__((address_space(3))) void*)&As[ch0 * 8 - lane * 8], 16, 0, 0);
        __builtin_amdgcn_global_load_lds(
            (const __attribute__((address_space(1))) void*)&A[(size_t)(m0 + row1) * DSTATE + kt + q1 * 8],
            (__attribute__((address_space(3))) void*)&As[ch1 * 8 - lane * 8], 16, 0, 0);
        __builtin_amdgcn_global_load_lds(
            (const __attribute__((address_space(1))) void*)&Bt[(size_t)(n0 + row0) * DSTATE + kt + q0 * 8],
            (__attribute__((address_space(3))) void*)&Bs[ch0 * 8 - lane * 8], 16, 0, 0);
        __builtin_amdgcn_global_load_lds(
            (const __attribute__((address_space(1))) void*)&Bt[(size_t)(n0 + row1) * DSTATE + kt + q1 * 8],
            (__attribute__((address_space(3))) void*)&Bs[ch1 * 8 - lane * 8], 16, 0, 0);
        __syncthreads();

        bf16x8 af[4], bf[4];
        #pragma unroll
        for (int f = 0; f < 4; ++f) {
            af[f] = *(const bf16x8*)&As[(wm * 64 + f * 16 + mr) * 32 + g * 8];
            bf[f] = *(const bf16x8*)&Bs[(wn * 64 + f * 16 + mr) * 32 + g * 8];
        }
        #pragma unroll
        for (int fm = 0; fm < 4; ++fm)
            #pragma unroll
            for (int fn = 0; fn < 4; ++fn)
                acc[fm][fn] = __builtin_amdgcn_mfma_f32_16x16x32_bf16(af[fm], bf[fn], acc[fm][fn], 0, 0, 0);
        __syncthreads();
    }
    #pragma unroll
    for (int fm = 0; fm < 4; ++fm) {
        #pragma unroll
        for (int fn = 0; fn < 4; ++fn) {
            int col = n0 + wn * 64 + fn * 16 + mr;
            if (col >= NCLS) continue;
            float bias = bo[col];
            #pragma unroll
            for (int r = 0; r < 4; ++r) {
                int row = m0 + wm * 64 + fm * 16 + g * 4 + r;
                C[(size_t)row * NCLS + col] = acc[fm][fn][r] + bias;
            }
        }
    }
}

// ---- softmax + loss ------------------------------------------------------
__device__ inline float wave_reduce_max(float v) {
    #pragma unroll
    for (int off = 32; off > 0; off >>= 1) v = fmaxf(v, __shfl_xor(v, off));
    return v;
}
__device__ inline float wave_reduce_sum(float v) {
    #pragma unroll
    for (int off = 32; off > 0; off >>= 1) v += __shfl_xor(v, off);
    return v;
}

// bf16-input softmax (chunked path): logits from LLC, dot from GEMM partials.
__launch_bounds__(256)
__global__ void softmax_loss_bf16(const unsigned short* __restrict__ Cb,  // [chunk][NCLS]
                                  const float* __restrict__ dotp,         // [chunk][NSLOT_PAD]
                                  float* __restrict__ probs,              // chunk base
                                  float* __restrict__ rowloss) {          // chunk base
    __shared__ float row[NCLS];          // 40 KB
    __shared__ float sm[4];
    const int tid = threadIdx.x;
    const size_t base = (size_t)blockIdx.x * NCLS;

    float m = -INFINITY;
    for (int c8 = tid; c8 < NCLS / 8; c8 += 256) {
        ushort4 u0 = *(const ushort4*)&Cb[base + c8 * 8];
        ushort4 u1 = *(const ushort4*)&Cb[base + c8 * 8 + 4];
        float v0 = b2f(u0.x), v1 = b2f(u0.y), v2 = b2f(u0.z), v3 = b2f(u0.w);
        float v4 = b2f(u1.x), v5 = b2f(u1.y), v6 = b2f(u1.z), v7 = b2f(u1.w);
        float4 a = {v0, v1, v2, v3}, b = {v4, v5, v6, v7};
        *(float4*)&row[c8 * 8] = a;
        *(float4*)&row[c8 * 8 + 4] = b;
        m = fmaxf(m, fmaxf(fmaxf(fmaxf(v0, v1), fmaxf(v2, v3)),
                           fmaxf(fmaxf(v4, v5), fmaxf(v6, v7))));
    }
    m = wave_reduce_max(m);
    if ((tid & 63) == 0) sm[tid >> 6] = m;
    __syncthreads();
    m = fmaxf(fmaxf(sm[0], sm[1]), fmaxf(sm[2], sm[3]));
    __syncthreads();

    float s = 0.f;
    float dot = (tid < NSLOT) ? dotp[(size_t)blockIdx.x * NSLOT_PAD + tid] : 0.f;
    for (int c4 = tid; c4 < NCLS / 4; c4 += 256) {
        float4 v = *(const float4*)&row[c4 * 4];
        s += expf(v.x - m) + expf(v.y - m) + expf(v.z - m) + expf(v.w - m);
    }
    s = wave_reduce_sum(s);
    if ((tid & 63) == 0) sm[tid >> 6] = s;
    __syncthreads();
    s = sm[0] + sm[1] + sm[2] + sm[3];
    __syncthreads();
    dot = wave_reduce_sum(dot);
    if ((tid & 63) == 0) sm[tid >> 6] = dot;
    __syncthreads();
    dot = sm[0] + sm[1] + sm[2] + sm[3];

    float inv = 1.f / s;
    for (int c4 = tid; c4 < NCLS / 4; c4 += 256) {
        float4 v = *(const float4*)&row[c4 * 4];
        float4 o;
        o.x = expf(v.x - m) * inv; o.y = expf(v.y - m) * inv;
        o.z = expf(v.z - m) * inv; o.w = expf(v.w - m) * inv;
        *(float4*)&probs[base + c4 * 4] = o;
    }
    if (tid == 0) rowloss[blockIdx.x] = (m + logf(s)) - dot;
}

// f32 in-place softmax (fallback path)
__launch_bounds__(256)
__global__ void softmax_loss(float* __restrict__ logits,
                             const float* __restrict__ labels,
                             float* __restrict__ rowloss) {
    __shared__ float row[NCLS];
    __shared__ float sm[4];
    const int tid = threadIdx.x;
    const size_t base = (size_t)blockIdx.x * NCLS;

    float m = -INFINITY;
    for (int c4 = tid; c4 < NCLS / 4; c4 += 256) {
        float4 v = *(const float4*)&logits[base + c4 * 4];
        *(float4*)&row[c4 * 4] = v;
        m = fmaxf(fmaxf(m, fmaxf(v.x, v.y)), fmaxf(v.z, v.w));
    }
    m = wave_reduce_max(m);
    if ((tid & 63) == 0) sm[tid >> 6] = m;
    __syncthreads();
    m = fmaxf(fmaxf(sm[0], sm[1]), fmaxf(sm[2], sm[3]));
    __syncthreads();

    float s = 0.f, dot = 0.f;
    for (int c4 = tid; c4 < NCLS / 4; c4 += 256) {
        float4 v = *(const float4*)&row[c4 * 4];
        float4 lb = *(const float4*)&labels[base + c4 * 4];
        s += expf(v.x - m) + expf(v.y - m) + expf(v.z - m) + expf(v.w - m);
        dot += lb.x * v.x + lb.y * v.y + lb.z * v.z + lb.w * v.w;
    }
    s = wave_reduce_sum(s);
    if ((tid & 63) == 0) sm[tid >> 6] = s;
    __syncthreads();
    s = sm[0] + sm[1] + sm[2] + sm[3];
    __syncthreads();
    dot = wave_reduce_sum(dot);
    if ((tid & 63) == 0) sm[tid >> 6] = dot;
    __syncthreads();
    dot = sm[0] + sm[1] + sm[2] + sm[3];

    float inv = 1.f / s;
    for (int c4 = tid; c4 < NCLS / 4; c4 += 256) {
        float4 v = *(const float4*)&row[c4 * 4];
        float4 o;
        o.x = expf(v.x - m) * inv; o.y = expf(v.y - m) * inv;
        o.z = expf(v.z - m) * inv; o.w = expf(v.w - m) * inv;
        *(float4*)&logits[base + c4 * 4] = o;
    }
    if (tid == 0) rowloss[blockIdx.x] = (m + logf(s)) - dot;
}

__launch_bounds__(256)
__global__ void loss_reduce(const float* __restrict__ rowloss, float* __restrict__ out) {
    __shared__ float sm[4];
    float s = 0.f;
    for (int i = threadIdx.x; i < ROWS; i += 256) s += rowloss[i];
    s = wave_reduce_sum(s);
    if ((threadIdx.x & 63) == 0) sm[threadIdx.x >> 6] = s;
    __syncthreads();
    if (threadIdx.x == 0) out[0] = (sm[0] + sm[1] + sm[2] + sm[3]) * (1.f / ROWS);
}

// ---- launcher ------------------------------------------------------------
extern "C" void kernel_launch(void* const* d_in, const int* in_sizes, int n_in,
                              void* d_out, int out_size, void* d_ws, size_t ws_size,
                              hipStream_t stream) {
    const float* inputs = (const float*)d_in[0];
    const float* labels = (const float*)d_in[1];
    const float* c0     = (const float*)d_in[2];   // initial_state (cell)
    const float* h0     = (const float*)d_in[3];   // initial_output (hidden)
    const float* Wx     = (const float*)d_in[4];
    const float* Wh     = (const float*)d_in[5];
    const float* bias   = (const float*)d_in[6];
    const float* Wo     = (const float*)d_in[7];
    const float* bo     = (const float*)d_in[8];
    float* out = (float*)d_out;

    float* ws = (float*)d_ws;
    float* bp       = ws;                                  // 2048 f32
    float* rowloss  = bp + 2048;                           // 16384 f32
    unsigned short* WhT = (unsigned short*)(rowloss + 16384); // 2048*512
    unsigned short* WxT = WhT + 1048576;                   // 2048*256
    unsigned short* Xb  = WxT + 524288;                    // 16384*256
    unsigned short* h0b = Xb + 4194304;                    // 64*512
    unsigned short* hsb = h0b + 32768;                     // 16384*512
    unsigned short* WoT = hsb + 8388608;                   // 10112*512
    unsigned short* ZxT = WoT + 5177344;                   // 256*2048*64
    unsigned* bar = (unsigned*)(ZxT + 33554432);           // 256 words (4 groups x 64)
    unsigned short* Cb = (unsigned short*)(bar + 256);     // CHUNK_ROWS*NCLS bf16
    float* dotp = (float*)(Cb + (size_t)CHUNK_ROWS * NCLS); // CHUNK_ROWS*NSLOT_PAD f32

    size_t base_bytes = (size_t)((char*)dotp - (char*)d_ws);
    size_t need_bf16 = base_bytes + (size_t)CHUNK_ROWS * NSLOT_PAD * sizeof(float);
    bool use_bf16 = (ws_size >= need_bf16);

    prep_all<<<11545, 256, 0, stream>>>(inputs, Wx, Wh, bias, h0, Wo,
                                        Xb, WxT, WhT, bp, h0b, bar, WoT);

    zx_gemm<<<dim3(T_STEPS, NGATE / 128), 256, 0, stream>>>(Xb, WxT, bp, ZxT);

    void* args[] = {(void*)&h0b, (void*)&c0, (void*)&WhT, (void*)&ZxT, (void*)&hsb, (void*)&bar};
    hipLaunchCooperativeKernel((const void*)lstm_scan_mfma, dim3(SCAN_BLOCKS), dim3(256),
                               args, 0, stream);

    if (use_bf16) {
        for (int row0 = 0; row0 < ROWS; row0 += CHUNK_ROWS) {
            gemm_logits_bf16<<<2528, 256, 0, stream>>>(
                hsb + (size_t)row0 * DSTATE, WoT, bo,
                labels + (size_t)row0 * NCLS, Cb, dotp);
            softmax_loss_bf16<<<CHUNK_ROWS, 256, 0, stream>>>(
                Cb, dotp, out + (size_t)row0 * NCLS, rowloss + row0);
        }
    } else {
        gemm_logits_mfma<<<dim3(NCLS_PAD / 128, ROWS / 128), 256, 0, stream>>>(hsb, WoT, bo, out);
        softmax_loss<<<ROWS, 256, 0, stream>>>(out, labels, rowloss);
    }
    loss_reduce<<<1, 256, 0, stream>>>(rowloss, out + (size_t)ROWS * NCLS);
}

// Round 11
// 1959.271 us; speedup vs baseline: 1.0692x; 1.0692x over previous
//
#include <hip/hip_runtime.h>
#include <hip/hip_bf16.h>
#include <math.h>

#define T_STEPS 256
#define BATCH 64
#define DIN 256
#define DSTATE 512
#define NGATE 2048   // 4*DSTATE
#define NCLS 10000
#define NCLS_PAD 10112   // 79 * 128
#define ROWS 16384   // T_STEPS*BATCH
#define SCAN_BLOCKS 64
#define GROUP_BLOCKS 16  // blocks per batch-group (barrier scope)
#define CHUNK_ROWS 4096  // rows per logits/softmax chunk (bf16 path)

typedef __attribute__((ext_vector_type(8))) short bf16x8;
typedef __attribute__((ext_vector_type(4))) float f32x4;

__device__ inline unsigned short f2b(float x) {
    __hip_bfloat16 h = __float2bfloat16(x);
    return *(unsigned short*)&h;
}
__device__ inline float b2f(unsigned short u) {
    return __uint_as_float(((unsigned int)u) << 16);
}

// ---- prep kernels (r9-verified) ------------------------------------------

__global__ void init_bar(unsigned* __restrict__ bar) {
    bar[blockIdx.x * 256 + threadIdx.x] = 0u;   // 1024 words: 4 groups x 16 flags x 16-word stride
}

__global__ void f32_to_bf16(const float* __restrict__ in, unsigned short* __restrict__ out, int n4) {
    int i = blockIdx.x * 256 + threadIdx.x;
    if (i >= n4) return;
    float4 v = *(const float4*)&in[i * 4];
    ushort4 o;
    o.x = f2b(v.x); o.y = f2b(v.y); o.z = f2b(v.z); o.w = f2b(v.w);
    *(ushort4*)&out[i * 4] = o;
}

__global__ void build_wT(const float* __restrict__ W, unsigned short* __restrict__ WT,
                         int kshift, int total) {
    int e = blockIdx.x * 256 + threadIdx.x;
    if (e >= total) return;
    int jp = e >> kshift;
    int k = e & ((1 << kshift) - 1);
    int s = jp >> 2, g = jp & 3;
    WT[e] = f2b(W[(size_t)k * NGATE + g * DSTATE + s]);
}

__global__ void build_bias(const float* __restrict__ b, float* __restrict__ bp) {
    int jp = blockIdx.x * 256 + threadIdx.x;
    if (jp >= NGATE) return;
    bp[jp] = b[(jp & 3) * DSTATE + (jp >> 2)];
}

__launch_bounds__(256)
__global__ void transpose_wo(const float* __restrict__ Wo, unsigned short* __restrict__ WoT) {
    __shared__ float tile[64][65];
    const int tid = threadIdx.x;
    const int n0 = blockIdx.x * 64, k0 = blockIdx.y * 64;
    #pragma unroll
    for (int r = 0; r < 16; ++r) {
        int k = (tid >> 6) + r * 4;
        int n = tid & 63;
        float v = (n0 + n < NCLS) ? Wo[(size_t)(k0 + k) * NCLS + n0 + n] : 0.f;
        tile[k][n] = v;
    }
    __syncthreads();
    #pragma unroll
    for (int r = 0; r < 16; ++r) {
        int n = (tid >> 6) + r * 4;
        int k = tid & 63;
        WoT[(size_t)(n0 + n) * DSTATE + k0 + k] = f2b(tile[k][n]);
    }
}

// ---- Zx = X @ Wx (+bias), output transposed: ZxT[t][jp][b] bf16 ---------
__launch_bounds__(256)
__global__ void zx_gemm(const unsigned short* __restrict__ Xb,   // [16384][256]
                        const unsigned short* __restrict__ WxT,  // [2048][256]
                        const float* __restrict__ bp,            // [2048]
                        unsigned short* __restrict__ ZxT) {      // [256][2048][64]
    __shared__ unsigned short As[64][264];
    __shared__ unsigned short Bs[128][264];
    __shared__ float zls[4][32][65];
    const int tid = threadIdx.x;
    const int t = blockIdx.x;
    const int n0 = blockIdx.y * 128;
    const int wave = tid >> 6, lane = tid & 63, mr = lane & 15, g = lane >> 4;

    #pragma unroll
    for (int r = 0; r < 8; ++r) {
        int c = r * 256 + tid; int row = c >> 5, q = c & 31;
        *(int4*)&As[row][q * 8] = *(const int4*)&Xb[((size_t)t * 64 + row) * DIN + q * 8];
    }
    #pragma unroll
    for (int r = 0; r < 16; ++r) {
        int c = r * 256 + tid; int row = c >> 5, q = c & 31;
        *(int4*)&Bs[row][q * 8] = *(const int4*)&WxT[(size_t)(n0 + row) * DIN + q * 8];
    }
    __syncthreads();

    f32x4 acc[4][2] = {};
    #pragma unroll
    for (int kt = 0; kt < DIN; kt += 32) {
        bf16x8 af[4], bf[2];
        #pragma unroll
        for (int fm = 0; fm < 4; ++fm) af[fm] = *(const bf16x8*)&As[fm * 16 + mr][kt + g * 8];
        #pragma unroll
        for (int fn = 0; fn < 2; ++fn) bf[fn] = *(const bf16x8*)&Bs[wave * 32 + fn * 16 + mr][kt + g * 8];
        #pragma unroll
        for (int fm = 0; fm < 4; ++fm)
            #pragma unroll
            for (int fn = 0; fn < 2; ++fn)
                acc[fm][fn] = __builtin_amdgcn_mfma_f32_16x16x32_bf16(af[fm], bf[fn], acc[fm][fn], 0, 0, 0);
    }
    #pragma unroll
    for (int fm = 0; fm < 4; ++fm)
        #pragma unroll
        for (int fn = 0; fn < 2; ++fn)
            #pragma unroll
            for (int r = 0; r < 4; ++r)
                zls[wave][fn * 16 + mr][fm * 16 + g * 4 + r] = acc[fm][fn][r];
    #pragma unroll 4
    for (int jr = 0; jr < 32; ++jr) {
        int j = n0 + wave * 32 + jr;
        float v = zls[wave][jr][lane] + bp[j];
        ZxT[((size_t)t * NGATE + j) * 64 + lane] = f2b(v);
    }
}

// ---- distributed-flag GROUP barrier: 16 flags on separate 64B lines ------
// Arrival = one release-store (single hop). Lanes 0..15 relax-poll all flags,
// then ONE vector acquire load (pairs with every producer's release; one
// buffer_inv for the wave), then block-wide __syncthreads.
__device__ __forceinline__ void groupbar(unsigned* fbase, int w, unsigned want, int tid) {
    __syncthreads();   // drains vmcnt: all h-stores of this block are complete
    if (tid == 0)
        __hip_atomic_store(&fbase[w * 16], want, __ATOMIC_RELEASE, __HIP_MEMORY_SCOPE_AGENT);
    if (tid < GROUP_BLOCKS) {
        while (__hip_atomic_load(&fbase[tid * 16], __ATOMIC_RELAXED, __HIP_MEMORY_SCOPE_AGENT) < want) {}
        (void)__hip_atomic_load(&fbase[tid * 16], __ATOMIC_ACQUIRE, __HIP_MEMORY_SCOPE_AGENT);
    }
    __syncthreads();
}

// ---- cooperative LSTM scan, batch-grouped: 4 groups x 16 blocks ----------
__launch_bounds__(256, 1)
__global__ void lstm_scan_mfma(const unsigned short* __restrict__ h0b,  // [64][512] bf16
                               const float* __restrict__ c0,            // [64][512] f32
                               const unsigned short* __restrict__ WhT,  // [2048][512] bf16
                               const unsigned short* __restrict__ ZxT,  // [256][2048][64] bf16
                               unsigned short* __restrict__ hsb,        // [256][64][512] bf16
                               unsigned* __restrict__ bar) {
    __shared__ unsigned short Wl[128][520];  // 133,120 B
    __shared__ unsigned short hT[16][520];   //  16,640 B
    __shared__ float zb[16][132];            //   8,448 B
    const int tid = threadIdx.x;
    const int bid = blockIdx.x;
    const int grp = bid >> 4;
    const int w   = bid & 15;
    const int b0  = grp * 16;
    const int j0  = w * 128;
    const int s0  = w * 32;
    const int wave = tid >> 6, lane = tid & 63, mr = lane & 15, gl = lane >> 4;
    unsigned* fbase = bar + grp * 256;   // 16 flags x 16-word stride

    #pragma unroll 4
    for (int r = 0; r < 32; ++r) {
        int c = r * 256 + tid; int row = c >> 6, q = c & 63;
        *(int4*)&Wl[row][q * 8] = *(const int4*)&WhT[(size_t)(j0 + row) * DSTATE + q * 8];
    }

    const int gb  = lane >> 2;
    const int slg = wave * 8 + (lane & 3) * 2;
    float creg0 = c0[(b0 + gb) * DSTATE + s0 + slg];
    float creg1 = c0[(b0 + gb) * DSTATE + s0 + slg + 1];
    __syncthreads();

    const size_t zo0 = ((size_t)(j0 + wave * 32 + mr)) * 64 + b0 + gl * 4;
    const size_t zo1 = ((size_t)(j0 + wave * 32 + 16 + mr)) * 64 + b0 + gl * 4;
    ushort4 za0 = *(const ushort4*)&ZxT[zo0];
    ushort4 za1 = *(const ushort4*)&ZxT[zo1];

    for (int t = 0; t < T_STEPS; ++t) {
        const unsigned short* hsrc = t ? (hsb + (size_t)(t - 1) * BATCH * DSTATE) : h0b;
        #pragma unroll
        for (int r = 0; r < 4; ++r) {
            int c = r * 256 + tid; int row = c >> 6, q = c & 63;
            *(int4*)&hT[row][q * 8] = *(const int4*)&hsrc[(size_t)(b0 + row) * DSTATE + q * 8];
        }
        __syncthreads();

        f32x4 acc0, acc1;
        acc0[0] = b2f(za0.x); acc0[1] = b2f(za0.y); acc0[2] = b2f(za0.z); acc0[3] = b2f(za0.w);
        acc1[0] = b2f(za1.x); acc1[1] = b2f(za1.y); acc1[2] = b2f(za1.z); acc1[3] = b2f(za1.w);
        if (t + 1 < T_STEPS) {
            za0 = *(const ushort4*)&ZxT[(size_t)(t + 1) * NGATE * 64 + zo0];
            za1 = *(const ushort4*)&ZxT[(size_t)(t + 1) * NGATE * 64 + zo1];
        }
        #pragma unroll
        for (int kt = 0; kt < DSTATE; kt += 32) {
            bf16x8 af = *(const bf16x8*)&hT[mr][kt + gl * 8];
            acc0 = __builtin_amdgcn_mfma_f32_16x16x32_bf16(af, *(const bf16x8*)&Wl[wave * 32 + mr][kt + gl * 8], acc0, 0, 0, 0);
            acc1 = __builtin_amdgcn_mfma_f32_16x16x32_bf16(af, *(const bf16x8*)&Wl[wave * 32 + 16 + mr][kt + gl * 8], acc1, 0, 0, 0);
        }
        #pragma unroll
        for (int r = 0; r < 4; ++r) {
            zb[gl * 4 + r][wave * 32 + mr] = acc0[r];
            zb[gl * 4 + r][wave * 32 + 16 + mr] = acc1[r];
        }
        {
            float zi0 = zb[gb][slg * 4 + 0], zf0 = zb[gb][slg * 4 + 1];
            float zg0 = zb[gb][slg * 4 + 2], zo0v = zb[gb][slg * 4 + 3];
            float zi1 = zb[gb][slg * 4 + 4], zf1 = zb[gb][slg * 4 + 5];
            float zg1 = zb[gb][slg * 4 + 6], zo1v = zb[gb][slg * 4 + 7];
            float i0 = 1.f / (1.f + expf(-zi0)), f0 = 1.f / (1.f + expf(-zf0));
            float o0 = 1.f / (1.f + expf(-zo0v)), g0 = tanhf(zg0);
            float i1 = 1.f / (1.f + expf(-zi1)), f1 = 1.f / (1.f + expf(-zf1));
            float o1 = 1.f / (1.f + expf(-zo1v)), g1 = tanhf(zg1);
            creg0 = f0 * creg0 + i0 * g0;
            creg1 = f1 * creg1 + i1 * g1;
            float h0v = o0 * tanhf(creg0);
            float h1v = o1 * tanhf(creg1);
            ushort2 hv; hv.x = f2b(h0v); hv.y = f2b(h1v);
            *(ushort2*)&hsb[((size_t)t * BATCH + b0 + gb) * DSTATE + s0 + slg] = hv;
        }
        if (t != T_STEPS - 1)
            groupbar(fbase, w, (unsigned)(t + 1), tid);
    }
}

// ---- logits GEMM, bf16 C output (chunked path, r9-verified) --------------
__launch_bounds__(256)
__global__ void gemm_logits_bf16(const unsigned short* __restrict__ A,   // [chunk_rows][512]
                                 const unsigned short* __restrict__ Bt,  // [NCLS_PAD][512]
                                 const float* __restrict__ bo,
                                 unsigned short* __restrict__ Cb) {      // [chunk_rows][NCLS]
    __shared__ unsigned short As[128 * 32];
    __shared__ unsigned short Bs[128 * 32];
    const int tid = threadIdx.x;
    const int wave = tid >> 6, lane = tid & 63;
    const int wm = wave >> 1, wn = wave & 1;
    const int m0 = blockIdx.y * 128, n0 = blockIdx.x * 128;
    const int g = lane >> 4, mr = lane & 15;

    const int ch0 = wave * 64 + lane;
    const int ch1 = (4 + wave) * 64 + lane;
    const int row0 = ch0 >> 2, q0 = ch0 & 3;
    const int row1 = ch1 >> 2, q1 = ch1 & 3;

    f32x4 acc[4][4] = {};
    for (int kt = 0; kt < DSTATE; kt += 32) {
        __builtin_amdgcn_global_load_lds(
            (const __attribute__((address_space(1))) void*)&A[(size_t)(m0 + row0) * DSTATE + kt + q0 * 8],
            (__attribute__((address_space(3))) void*)&As[ch0 * 8 - lane * 8], 16, 0, 0);
        __builtin_amdgcn_global_load_lds(
            (const __attribute__((address_space(1))) void*)&A[(size_t)(m0 + row1) * DSTATE + kt + q1 * 8],
            (__attribute__((address_space(3))) void*)&As[ch1 * 8 - lane * 8], 16, 0, 0);
        __builtin_amdgcn_global_load_lds(
            (const __attribute__((address_space(1))) void*)&Bt[(size_t)(n0 + row0) * DSTATE + kt + q0 * 8],
            (__attribute__((address_space(3))) void*)&Bs[ch0 * 8 - lane * 8], 16, 0, 0);
        __builtin_amdgcn_global_load_lds(
            (const __attribute__((address_space(1))) void*)&Bt[(size_t)(n0 + row1) * DSTATE + kt + q1 * 8],
            (__attribute__((address_space(3))) void*)&Bs[ch1 * 8 - lane * 8], 16, 0, 0);
        __syncthreads();

        bf16x8 af[4], bf[4];
        #pragma unroll
        for (int f = 0; f < 4; ++f) {
            af[f] = *(const bf16x8*)&As[(wm * 64 + f * 16 + mr) * 32 + g * 8];
            bf[f] = *(const bf16x8*)&Bs[(wn * 64 + f * 16 + mr) * 32 + g * 8];
        }
        #pragma unroll
        for (int fm = 0; fm < 4; ++fm)
            #pragma unroll
            for (int fn = 0; fn < 4; ++fn)
                acc[fm][fn] = __builtin_amdgcn_mfma_f32_16x16x32_bf16(af[fm], bf[fn], acc[fm][fn], 0, 0, 0);
        __syncthreads();
    }
    #pragma unroll
    for (int fm = 0; fm < 4; ++fm) {
        #pragma unroll
        for (int fn = 0; fn < 4; ++fn) {
            int col = n0 + wn * 64 + fn * 16 + mr;
            if (col >= NCLS) continue;
            float bias = bo[col];
            #pragma unroll
            for (int r = 0; r < 4; ++r) {
                int row = m0 + wm * 64 + fm * 16 + g * 4 + r;
                Cb[(size_t)row * NCLS + col] = f2b(acc[fm][fn][r] + bias);
            }
        }
    }
}

// ---- logits GEMM, f32 C (fallback path) ----------------------------------
__launch_bounds__(256)
__global__ void gemm_logits_mfma(const unsigned short* __restrict__ A,
                                 const unsigned short* __restrict__ Bt,
                                 const float* __restrict__ bo,
                                 float* __restrict__ C) {
    __shared__ unsigned short As[128 * 32];
    __shared__ unsigned short Bs[128 * 32];
    const int tid = threadIdx.x;
    const int wave = tid >> 6, lane = tid & 63;
    const int wm = wave >> 1, wn = wave & 1;
    const int m0 = blockIdx.y * 128, n0 = blockIdx.x * 128;
    const int g = lane >> 4, mr = lane & 15;

    const int ch0 = wave * 64 + lane;
    const int ch1 = (4 + wave) * 64 + lane;
    const int row0 = ch0 >> 2, q0 = ch0 & 3;
    const int row1 = ch1 >> 2, q1 = ch1 & 3;

    f32x4 acc[4][4] = {};
    for (int kt = 0; kt < DSTATE; kt += 32) {
        __builtin_amdgcn_global_load_lds(
            (const __attribute__((address_space(1))) void*)&A[(size_t)(m0 + row0) * DSTATE + kt + q0 * 8],
            (__attribute__((address_space(3))) void*)&As[ch0 * 8 - lane * 8], 16, 0, 0);
        __builtin_amdgcn_global_load_lds(
            (const __attribute__((address_space(1))) void*)&A[(size_t)(m0 + row1) * DSTATE + kt + q1 * 8],
            (__attribute__((address_space(3))) void*)&As[ch1 * 8 - lane * 8], 16, 0, 0);
        __builtin_amdgcn_global_load_lds(
            (const __attribute__((address_space(1))) void*)&Bt[(size_t)(n0 + row0) * DSTATE + kt + q0 * 8],
            (__attribute__((address_space(3))) void*)&Bs[ch0 * 8 - lane * 8], 16, 0, 0);
        __builtin_amdgcn_global_load_lds(
            (const __attribute__((address_space(1))) void*)&Bt[(size_t)(n0 + row1) * DSTATE + kt + q1 * 8],
            (__attribute__((address_space(3))) void*)&Bs[ch1 * 8 - lane * 8], 16, 0, 0);
        __syncthreads();

        bf16x8 af[4], bf[4];
        #pragma unroll
        for (int f = 0; f < 4; ++f) {
            af[f] = *(const bf16x8*)&As[(wm * 64 + f * 16 + mr) * 32 + g * 8];
            bf[f] = *(const bf16x8*)&Bs[(wn * 64 + f * 16 + mr) * 32 + g * 8];
        }
        #pragma unroll
        for (int fm = 0; fm < 4; ++fm)
            #pragma unroll
            for (int fn = 0; fn < 4; ++fn)
                acc[fm][fn] = __builtin_amdgcn_mfma_f32_16x16x32_bf16(af[fm], bf[fn], acc[fm][fn], 0, 0, 0);
        __syncthreads();
    }
    #pragma unroll
    for (int fm = 0; fm < 4; ++fm) {
        #pragma unroll
        for (int fn = 0; fn < 4; ++fn) {
            int col = n0 + wn * 64 + fn * 16 + mr;
            if (col >= NCLS) continue;
            float bias = bo[col];
            #pragma unroll
            for (int r = 0; r < 4; ++r) {
                int row = m0 + wm * 64 + fm * 16 + g * 4 + r;
                C[(size_t)row * NCLS + col] = acc[fm][fn][r] + bias;
            }
        }
    }
}

// ---- softmax + loss ------------------------------------------------------
__device__ inline float wave_reduce_max(float v) {
    #pragma unroll
    for (int off = 32; off > 0; off >>= 1) v = fmaxf(v, __shfl_xor(v, off));
    return v;
}
__device__ inline float wave_reduce_sum(float v) {
    #pragma unroll
    for (int off = 32; off > 0; off >>= 1) v += __shfl_xor(v, off);
    return v;
}

// bf16-input softmax (chunked path, r9-verified)
__launch_bounds__(256)
__global__ void softmax_loss_bf16(const unsigned short* __restrict__ Cb,  // [chunk][NCLS]
                                  const float* __restrict__ labels,       // chunk base
                                  float* __restrict__ probs,              // chunk base
                                  float* __restrict__ rowloss) {          // chunk base
    __shared__ float row[NCLS];          // 40 KB
    __shared__ float sm[4];
    const int tid = threadIdx.x;
    const size_t base = (size_t)blockIdx.x * NCLS;

    float m = -INFINITY;
    for (int c8 = tid; c8 < NCLS / 8; c8 += 256) {
        ushort4 u0 = *(const ushort4*)&Cb[base + c8 * 8];
        ushort4 u1 = *(const ushort4*)&Cb[base + c8 * 8 + 4];
        float v0 = b2f(u0.x), v1 = b2f(u0.y), v2 = b2f(u0.z), v3 = b2f(u0.w);
        float v4 = b2f(u1.x), v5 = b2f(u1.y), v6 = b2f(u1.z), v7 = b2f(u1.w);
        float4 a = {v0, v1, v2, v3}, b = {v4, v5, v6, v7};
        *(float4*)&row[c8 * 8] = a;
        *(float4*)&row[c8 * 8 + 4] = b;
        m = fmaxf(m, fmaxf(fmaxf(fmaxf(v0, v1), fmaxf(v2, v3)),
                           fmaxf(fmaxf(v4, v5), fmaxf(v6, v7))));
    }
    m = wave_reduce_max(m);
    if ((tid & 63) == 0) sm[tid >> 6] = m;
    __syncthreads();
    m = fmaxf(fmaxf(sm[0], sm[1]), fmaxf(sm[2], sm[3]));
    __syncthreads();

    float s = 0.f, dot = 0.f;
    for (int c4 = tid; c4 < NCLS / 4; c4 += 256) {
        float4 v = *(const float4*)&row[c4 * 4];
        float4 lb = *(const float4*)&labels[base + c4 * 4];
        s += expf(v.x - m) + expf(v.y - m) + expf(v.z - m) + expf(v.w - m);
        dot += lb.x * v.x + lb.y * v.y + lb.z * v.z + lb.w * v.w;
    }
    s = wave_reduce_sum(s);
    if ((tid & 63) == 0) sm[tid >> 6] = s;
    __syncthreads();
    s = sm[0] + sm[1] + sm[2] + sm[3];
    __syncthreads();
    dot = wave_reduce_sum(dot);
    if ((tid & 63) == 0) sm[tid >> 6] = dot;
    __syncthreads();
    dot = sm[0] + sm[1] + sm[2] + sm[3];

    float inv = 1.f / s;
    for (int c4 = tid; c4 < NCLS / 4; c4 += 256) {
        float4 v = *(const float4*)&row[c4 * 4];
        float4 o;
        o.x = expf(v.x - m) * inv; o.y = expf(v.y - m) * inv;
        o.z = expf(v.z - m) * inv; o.w = expf(v.w - m) * inv;
        *(float4*)&probs[base + c4 * 4] = o;
    }
    if (tid == 0) rowloss[blockIdx.x] = (m + logf(s)) - dot;
}

// f32 in-place softmax (fallback path)
__launch_bounds__(256)
__global__ void softmax_loss(float* __restrict__ logits,
                             const float* __restrict__ labels,
                             float* __restrict__ rowloss) {
    __shared__ float row[NCLS];
    __shared__ float sm[4];
    const int tid = threadIdx.x;
    const size_t base = (size_t)blockIdx.x * NCLS;

    float m = -INFINITY;
    for (int c4 = tid; c4 < NCLS / 4; c4 += 256) {
        float4 v = *(const float4*)&logits[base + c4 * 4];
        *(float4*)&row[c4 * 4] = v;
        m = fmaxf(fmaxf(m, fmaxf(v.x, v.y)), fmaxf(v.z, v.w));
    }
    m = wave_reduce_max(m);
    if ((tid & 63) == 0) sm[tid >> 6] = m;
    __syncthreads();
    m = fmaxf(fmaxf(sm[0], sm[1]), fmaxf(sm[2], sm[3]));
    __syncthreads();

    float s = 0.f, dot = 0.f;
    for (int c4 = tid; c4 < NCLS / 4; c4 += 256) {
        float4 v = *(const float4*)&row[c4 * 4];
        float4 lb = *(const float4*)&labels[base + c4 * 4];
        s += expf(v.x - m) + expf(v.y - m) + expf(v.z - m) + expf(v.w - m);
        dot += lb.x * v.x + lb.y * v.y + lb.z * v.z + lb.w * v.w;
    }
    s = wave_reduce_sum(s);
    if ((tid & 63) == 0) sm[tid >> 6] = s;
    __syncthreads();
    s = sm[0] + sm[1] + sm[2] + sm[3];
    __syncthreads();
    dot = wave_reduce_sum(dot);
    if ((tid & 63) == 0) sm[tid >> 6] = dot;
    __syncthreads();
    dot = sm[0] + sm[1] + sm[2] + sm[3];

    float inv = 1.f / s;
    for (int c4 = tid; c4 < NCLS / 4; c4 += 256) {
        float4 v = *(const float4*)&row[c4 * 4];
        float4 o;
        o.x = expf(v.x - m) * inv; o.y = expf(v.y - m) * inv;
        o.z = expf(v.z - m) * inv; o.w = expf(v.w - m) * inv;
        *(float4*)&logits[base + c4 * 4] = o;
    }
    if (tid == 0) rowloss[blockIdx.x] = (m + logf(s)) - dot;
}

__launch_bounds__(256)
__global__ void loss_reduce(const float* __restrict__ rowloss, float* __restrict__ out) {
    __shared__ float sm[4];
    float s = 0.f;
    for (int i = threadIdx.x; i < ROWS; i += 256) s += rowloss[i];
    s = wave_reduce_sum(s);
    if ((threadIdx.x & 63) == 0) sm[threadIdx.x >> 6] = s;
    __syncthreads();
    if (threadIdx.x == 0) out[0] = (sm[0] + sm[1] + sm[2] + sm[3]) * (1.f / ROWS);
}

// ---- launcher ------------------------------------------------------------
extern "C" void kernel_launch(void* const* d_in, const int* in_sizes, int n_in,
                              void* d_out, int out_size, void* d_ws, size_t ws_size,
                              hipStream_t stream) {
    const float* inputs = (const float*)d_in[0];
    const float* labels = (const float*)d_in[1];
    const float* c0     = (const float*)d_in[2];   // initial_state (cell)
    const float* h0     = (const float*)d_in[3];   // initial_output (hidden)
    const float* Wx     = (const float*)d_in[4];
    const float* Wh     = (const float*)d_in[5];
    const float* bias   = (const float*)d_in[6];
    const float* Wo     = (const float*)d_in[7];
    const float* bo     = (const float*)d_in[8];
    float* out = (float*)d_out;

    float* ws = (float*)d_ws;
    float* bp       = ws;                                  // 2048 f32
    float* rowloss  = bp + 2048;                           // 16384 f32
    unsigned short* WhT = (unsigned short*)(rowloss + 16384); // 2048*512
    unsigned short* WxT = WhT + 1048576;                   // 2048*256
    unsigned short* Xb  = WxT + 524288;                    // 16384*256
    unsigned short* h0b = Xb + 4194304;                    // 64*512
    unsigned short* hsb = h0b + 32768;                     // 16384*512
    unsigned short* WoT = hsb + 8388608;                   // 10112*512
    unsigned short* ZxT = WoT + 5177344;                   // 256*2048*64
    unsigned* bar = (unsigned*)(ZxT + 33554432);           // 1024 words (4 grp x 16 flags x 16 stride)
    unsigned short* Cb = (unsigned short*)(bar + 1024);    // CHUNK_ROWS*NCLS bf16

    size_t base_bytes = (size_t)((char*)Cb - (char*)d_ws);
    size_t need_bf16 = base_bytes + (size_t)CHUNK_ROWS * NCLS * sizeof(unsigned short);
    bool use_bf16 = (ws_size >= need_bf16);

    init_bar<<<4, 256, 0, stream>>>(bar);
    f32_to_bf16<<<(ROWS * DIN / 4 + 255) / 256, 256, 0, stream>>>(inputs, Xb, ROWS * DIN / 4);
    f32_to_bf16<<<(BATCH * DSTATE / 4 + 255) / 256, 256, 0, stream>>>(h0, h0b, BATCH * DSTATE / 4);
    build_wT<<<(NGATE * DSTATE + 255) / 256, 256, 0, stream>>>(Wh, WhT, 9, NGATE * DSTATE);
    build_wT<<<(NGATE * DIN + 255) / 256, 256, 0, stream>>>(Wx, WxT, 8, NGATE * DIN);
    build_bias<<<(NGATE + 255) / 256, 256, 0, stream>>>(bias, bp);
    transpose_wo<<<dim3(NCLS_PAD / 64, DSTATE / 64), 256, 0, stream>>>(Wo, WoT);

    zx_gemm<<<dim3(T_STEPS, NGATE / 128), 256, 0, stream>>>(Xb, WxT, bp, ZxT);

    void* args[] = {(void*)&h0b, (void*)&c0, (void*)&WhT, (void*)&ZxT, (void*)&hsb, (void*)&bar};
    hipLaunchCooperativeKernel((const void*)lstm_scan_mfma, dim3(SCAN_BLOCKS), dim3(256),
                               args, 0, stream);

    if (use_bf16) {
        for (int row0 = 0; row0 < ROWS; row0 += CHUNK_ROWS) {
            gemm_logits_bf16<<<dim3(NCLS_PAD / 128, CHUNK_ROWS / 128), 256, 0, stream>>>(
                hsb + (size_t)row0 * DSTATE, WoT, bo, Cb);
            softmax_loss_bf16<<<CHUNK_ROWS, 256, 0, stream>>>(
                Cb, labels + (size_t)row0 * NCLS, out + (size_t)row0 * NCLS, rowloss + row0);
        }
    } else {
        gemm_logits_mfma<<<dim3(NCLS_PAD / 128, ROWS / 128), 256, 0, stream>>>(hsb, WoT, bo, out);
        softmax_loss<<<ROWS, 256, 0, stream>>>(out, labels, rowloss);
    }
    loss_reduce<<<1, 256, 0, stream>>>(rowloss, out + (size_t)ROWS * NCLS);
}

// Round 12
// 1894.466 us; speedup vs baseline: 1.1058x; 1.0342x over previous
//
#include <hip/hip_runtime.h>
#include <hip/hip_bf16.h>
#include <math.h>

#define T_STEPS 256
#define BATCH 64
#define DIN 256
#define DSTATE 512
#define NGATE 2048   // 4*DSTATE
#define NCLS 10000
#define NCLS_PAD 10112   // 79 * 128
#define ROWS 16384   // T_STEPS*BATCH
#define SCAN_BLOCKS 64
#define GROUP_BLOCKS 16  // blocks per batch-group (barrier scope)
#define CHUNK_ROWS 4096  // rows per logits/softmax chunk (bf16 path)

typedef __attribute__((ext_vector_type(8))) short bf16x8;
typedef __attribute__((ext_vector_type(4))) float f32x4;

__device__ inline unsigned short f2b(float x) {
    __hip_bfloat16 h = __float2bfloat16(x);
    return *(unsigned short*)&h;
}
__device__ inline float b2f(unsigned short u) {
    return __uint_as_float(((unsigned int)u) << 16);
}

// ---- fused prep: all independent format conversions in ONE launch --------
// sections: [0,4096) inputs->bf16 | [4096,8192) WhT | [8192,10240) WxT |
// [10240,10248) bias | [10248,10280) h0->bf16 | [10280,10284) bar |
// [10284,11548) WoT transpose
__launch_bounds__(256)
__global__ void prep_all(const float* __restrict__ inputs, const float* __restrict__ Wx,
                         const float* __restrict__ Wh, const float* __restrict__ bias,
                         const float* __restrict__ h0, const float* __restrict__ Wo,
                         unsigned short* __restrict__ Xb, unsigned short* __restrict__ WxT,
                         unsigned short* __restrict__ WhT, float* __restrict__ bp,
                         unsigned short* __restrict__ h0b, unsigned* __restrict__ bar,
                         unsigned short* __restrict__ WoT) {
    __shared__ float tile[64][65];
    const int bid = blockIdx.x;
    const int tid = threadIdx.x;
    if (bid < 4096) {                         // inputs -> bf16 (float4 quads)
        int i = bid * 256 + tid;
        float4 v = *(const float4*)&inputs[(size_t)i * 4];
        ushort4 o; o.x = f2b(v.x); o.y = f2b(v.y); o.z = f2b(v.z); o.w = f2b(v.w);
        *(ushort4*)&Xb[(size_t)i * 4] = o;
    } else if (bid < 8192) {                  // WhT: permute+transpose+cvt
        int e = (bid - 4096) * 256 + tid;
        int jp = e >> 9, k = e & 511;
        int s = jp >> 2, g = jp & 3;
        WhT[e] = f2b(Wh[(size_t)k * NGATE + g * DSTATE + s]);
    } else if (bid < 10240) {                 // WxT
        int e = (bid - 8192) * 256 + tid;
        int jp = e >> 8, k = e & 255;
        int s = jp >> 2, g = jp & 3;
        WxT[e] = f2b(Wx[(size_t)k * NGATE + g * DSTATE + s]);
    } else if (bid < 10248) {                 // bias permute
        int jp = (bid - 10240) * 256 + tid;
        if (jp < NGATE) bp[jp] = bias[(jp & 3) * DSTATE + (jp >> 2)];
    } else if (bid < 10280) {                 // h0 -> bf16
        int i = (bid - 10248) * 256 + tid;
        if (i < BATCH * DSTATE / 4) {
            float4 v = *(const float4*)&h0[(size_t)i * 4];
            ushort4 o; o.x = f2b(v.x); o.y = f2b(v.y); o.z = f2b(v.z); o.w = f2b(v.w);
            *(ushort4*)&h0b[(size_t)i * 4] = o;
        }
    } else if (bid < 10284) {                 // barrier words (1024)
        bar[(bid - 10280) * 256 + tid] = 0u;
    } else {                                  // WoT tiled transpose + cvt
        int nb = bid - 10284;                 // 0..1263  (158 x 8)
        int n0 = (nb % 158) * 64, k0 = (nb / 158) * 64;
        #pragma unroll
        for (int r = 0; r < 16; ++r) {
            int k = (tid >> 6) + r * 4;
            int n = tid & 63;
            float v = (n0 + n < NCLS) ? Wo[(size_t)(k0 + k) * NCLS + n0 + n] : 0.f;
            tile[k][n] = v;
        }
        __syncthreads();
        #pragma unroll
        for (int r = 0; r < 16; ++r) {
            int n = (tid >> 6) + r * 4;
            int k = tid & 63;
            WoT[(size_t)(n0 + n) * DSTATE + k0 + k] = f2b(tile[k][n]);
        }
    }
}

// ---- Zx = X @ Wx (+bias), output transposed: ZxT[t][jp][b] bf16 ---------
__launch_bounds__(256)
__global__ void zx_gemm(const unsigned short* __restrict__ Xb,   // [16384][256]
                        const unsigned short* __restrict__ WxT,  // [2048][256]
                        const float* __restrict__ bp,            // [2048]
                        unsigned short* __restrict__ ZxT) {      // [256][2048][64]
    __shared__ unsigned short As[64][264];
    __shared__ unsigned short Bs[128][264];
    __shared__ float zls[4][32][65];
    const int tid = threadIdx.x;
    const int t = blockIdx.x;
    const int n0 = blockIdx.y * 128;
    const int wave = tid >> 6, lane = tid & 63, mr = lane & 15, g = lane >> 4;

    #pragma unroll
    for (int r = 0; r < 8; ++r) {
        int c = r * 256 + tid; int row = c >> 5, q = c & 31;
        *(int4*)&As[row][q * 8] = *(const int4*)&Xb[((size_t)t * 64 + row) * DIN + q * 8];
    }
    #pragma unroll
    for (int r = 0; r < 16; ++r) {
        int c = r * 256 + tid; int row = c >> 5, q = c & 31;
        *(int4*)&Bs[row][q * 8] = *(const int4*)&WxT[(size_t)(n0 + row) * DIN + q * 8];
    }
    __syncthreads();

    f32x4 acc[4][2] = {};
    #pragma unroll
    for (int kt = 0; kt < DIN; kt += 32) {
        bf16x8 af[4], bf[2];
        #pragma unroll
        for (int fm = 0; fm < 4; ++fm) af[fm] = *(const bf16x8*)&As[fm * 16 + mr][kt + g * 8];
        #pragma unroll
        for (int fn = 0; fn < 2; ++fn) bf[fn] = *(const bf16x8*)&Bs[wave * 32 + fn * 16 + mr][kt + g * 8];
        #pragma unroll
        for (int fm = 0; fm < 4; ++fm)
            #pragma unroll
            for (int fn = 0; fn < 2; ++fn)
                acc[fm][fn] = __builtin_amdgcn_mfma_f32_16x16x32_bf16(af[fm], bf[fn], acc[fm][fn], 0, 0, 0);
    }
    #pragma unroll
    for (int fm = 0; fm < 4; ++fm)
        #pragma unroll
        for (int fn = 0; fn < 2; ++fn)
            #pragma unroll
            for (int r = 0; r < 4; ++r)
                zls[wave][fn * 16 + mr][fm * 16 + g * 4 + r] = acc[fm][fn][r];
    #pragma unroll 4
    for (int jr = 0; jr < 32; ++jr) {
        int j = n0 + wave * 32 + jr;
        float v = zls[wave][jr][lane] + bp[j];
        ZxT[((size_t)t * NGATE + j) * 64 + lane] = f2b(v);
    }
}

// ---- distributed-flag GROUP barrier (r11-verified) -----------------------
__device__ __forceinline__ void groupbar(unsigned* fbase, int w, unsigned want, int tid) {
    __syncthreads();   // drains vmcnt: all h-stores of this block are complete
    if (tid == 0)
        __hip_atomic_store(&fbase[w * 16], want, __ATOMIC_RELEASE, __HIP_MEMORY_SCOPE_AGENT);
    if (tid < GROUP_BLOCKS) {
        while (__hip_atomic_load(&fbase[tid * 16], __ATOMIC_RELAXED, __HIP_MEMORY_SCOPE_AGENT) < want) {}
        (void)__hip_atomic_load(&fbase[tid * 16], __ATOMIC_ACQUIRE, __HIP_MEMORY_SCOPE_AGENT);
    }
    __syncthreads();
}

// ---- cooperative LSTM scan, batch-grouped: 4 groups x 16 blocks (r11) ----
__launch_bounds__(256, 1)
__global__ void lstm_scan_mfma(const unsigned short* __restrict__ h0b,  // [64][512] bf16
                               const float* __restrict__ c0,            // [64][512] f32
                               const unsigned short* __restrict__ WhT,  // [2048][512] bf16
                               const unsigned short* __restrict__ ZxT,  // [256][2048][64] bf16
                               unsigned short* __restrict__ hsb,        // [256][64][512] bf16
                               unsigned* __restrict__ bar) {
    __shared__ unsigned short Wl[128][520];  // 133,120 B
    __shared__ unsigned short hT[16][520];   //  16,640 B
    __shared__ float zb[16][132];            //   8,448 B
    const int tid = threadIdx.x;
    const int bid = blockIdx.x;
    const int grp = bid >> 4;
    const int w   = bid & 15;
    const int b0  = grp * 16;
    const int j0  = w * 128;
    const int s0  = w * 32;
    const int wave = tid >> 6, lane = tid & 63, mr = lane & 15, gl = lane >> 4;
    unsigned* fbase = bar + grp * 256;   // 16 flags x 16-word stride

    #pragma unroll 4
    for (int r = 0; r < 32; ++r) {
        int c = r * 256 + tid; int row = c >> 6, q = c & 63;
        *(int4*)&Wl[row][q * 8] = *(const int4*)&WhT[(size_t)(j0 + row) * DSTATE + q * 8];
    }

    const int gb  = lane >> 2;
    const int slg = wave * 8 + (lane & 3) * 2;
    float creg0 = c0[(b0 + gb) * DSTATE + s0 + slg];
    float creg1 = c0[(b0 + gb) * DSTATE + s0 + slg + 1];
    __syncthreads();

    const size_t zo0 = ((size_t)(j0 + wave * 32 + mr)) * 64 + b0 + gl * 4;
    const size_t zo1 = ((size_t)(j0 + wave * 32 + 16 + mr)) * 64 + b0 + gl * 4;
    ushort4 za0 = *(const ushort4*)&ZxT[zo0];
    ushort4 za1 = *(const ushort4*)&ZxT[zo1];

    for (int t = 0; t < T_STEPS; ++t) {
        const unsigned short* hsrc = t ? (hsb + (size_t)(t - 1) * BATCH * DSTATE) : h0b;
        #pragma unroll
        for (int r = 0; r < 4; ++r) {
            int c = r * 256 + tid; int row = c >> 6, q = c & 63;
            *(int4*)&hT[row][q * 8] = *(const int4*)&hsrc[(size_t)(b0 + row) * DSTATE + q * 8];
        }
        __syncthreads();

        f32x4 acc0, acc1;
        acc0[0] = b2f(za0.x); acc0[1] = b2f(za0.y); acc0[2] = b2f(za0.z); acc0[3] = b2f(za0.w);
        acc1[0] = b2f(za1.x); acc1[1] = b2f(za1.y); acc1[2] = b2f(za1.z); acc1[3] = b2f(za1.w);
        if (t + 1 < T_STEPS) {
            za0 = *(const ushort4*)&ZxT[(size_t)(t + 1) * NGATE * 64 + zo0];
            za1 = *(const ushort4*)&ZxT[(size_t)(t + 1) * NGATE * 64 + zo1];
        }
        #pragma unroll
        for (int kt = 0; kt < DSTATE; kt += 32) {
            bf16x8 af = *(const bf16x8*)&hT[mr][kt + gl * 8];
            acc0 = __builtin_amdgcn_mfma_f32_16x16x32_bf16(af, *(const bf16x8*)&Wl[wave * 32 + mr][kt + gl * 8], acc0, 0, 0, 0);
            acc1 = __builtin_amdgcn_mfma_f32_16x16x32_bf16(af, *(const bf16x8*)&Wl[wave * 32 + 16 + mr][kt + gl * 8], acc1, 0, 0, 0);
        }
        #pragma unroll
        for (int r = 0; r < 4; ++r) {
            zb[gl * 4 + r][wave * 32 + mr] = acc0[r];
            zb[gl * 4 + r][wave * 32 + 16 + mr] = acc1[r];
        }
        {
            float zi0 = zb[gb][slg * 4 + 0], zf0 = zb[gb][slg * 4 + 1];
            float zg0 = zb[gb][slg * 4 + 2], zo0v = zb[gb][slg * 4 + 3];
            float zi1 = zb[gb][slg * 4 + 4], zf1 = zb[gb][slg * 4 + 5];
            float zg1 = zb[gb][slg * 4 + 6], zo1v = zb[gb][slg * 4 + 7];
            float i0 = 1.f / (1.f + expf(-zi0)), f0 = 1.f / (1.f + expf(-zf0));
            float o0 = 1.f / (1.f + expf(-zo0v)), g0 = tanhf(zg0);
            float i1 = 1.f / (1.f + expf(-zi1)), f1 = 1.f / (1.f + expf(-zf1));
            float o1 = 1.f / (1.f + expf(-zo1v)), g1 = tanhf(zg1);
            creg0 = f0 * creg0 + i0 * g0;
            creg1 = f1 * creg1 + i1 * g1;
            float h0v = o0 * tanhf(creg0);
            float h1v = o1 * tanhf(creg1);
            ushort2 hv; hv.x = f2b(h0v); hv.y = f2b(h1v);
            *(ushort2*)&hsb[((size_t)t * BATCH + b0 + gb) * DSTATE + s0 + slg] = hv;
        }
        if (t != T_STEPS - 1)
            groupbar(fbase, w, (unsigned)(t + 1), tid);
    }
}

// ---- logits GEMM, bf16 C via LDS-coalesced epilogue (chunked path) -------
__launch_bounds__(256)
__global__ void gemm_logits_bf16(const unsigned short* __restrict__ A,   // [chunk_rows][512]
                                 const unsigned short* __restrict__ Bt,  // [NCLS_PAD][512]
                                 const float* __restrict__ bo,
                                 unsigned short* __restrict__ Cb) {      // [chunk_rows][NCLS]
    __shared__ unsigned short As[128 * 32];
    __shared__ unsigned short Bs[128 * 32];
    __shared__ unsigned short sC[128][136];   // 16B-aligned rows (272 B stride)
    const int tid = threadIdx.x;
    const int wave = tid >> 6, lane = tid & 63;
    const int wm = wave >> 1, wn = wave & 1;
    const int m0 = blockIdx.y * 128, n0 = blockIdx.x * 128;
    const int g = lane >> 4, mr = lane & 15;

    const int ch0 = wave * 64 + lane;
    const int ch1 = (4 + wave) * 64 + lane;
    const int row0 = ch0 >> 2, q0 = ch0 & 3;
    const int row1 = ch1 >> 2, q1 = ch1 & 3;

    f32x4 acc[4][4] = {};
    for (int kt = 0; kt < DSTATE; kt += 32) {
        __builtin_amdgcn_global_load_lds(
            (const __attribute__((address_space(1))) void*)&A[(size_t)(m0 + row0) * DSTATE + kt + q0 * 8],
            (__attribute__((address_space(3))) void*)&As[ch0 * 8 - lane * 8], 16, 0, 0);
        __builtin_amdgcn_global_load_lds(
            (const __attribute__((address_space(1))) void*)&A[(size_t)(m0 + row1) * DSTATE + kt + q1 * 8],
            (__attribute__((address_space(3))) void*)&As[ch1 * 8 - lane * 8], 16, 0, 0);
        __builtin_amdgcn_global_load_lds(
            (const __attribute__((address_space(1))) void*)&Bt[(size_t)(n0 + row0) * DSTATE + kt + q0 * 8],
            (__attribute__((address_space(3))) void*)&Bs[ch0 * 8 - lane * 8], 16, 0, 0);
        __builtin_amdgcn_global_load_lds(
            (const __attribute__((address_space(1))) void*)&Bt[(size_t)(n0 + row1) * DSTATE + kt + q1 * 8],
            (__attribute__((address_space(3))) void*)&Bs[ch1 * 8 - lane * 8], 16, 0, 0);
        __syncthreads();

        bf16x8 af[4], bf[4];
        #pragma unroll
        for (int f = 0; f < 4; ++f) {
            af[f] = *(const bf16x8*)&As[(wm * 64 + f * 16 + mr) * 32 + g * 8];
            bf[f] = *(const bf16x8*)&Bs[(wn * 64 + f * 16 + mr) * 32 + g * 8];
        }
        #pragma unroll
        for (int fm = 0; fm < 4; ++fm)
            #pragma unroll
            for (int fn = 0; fn < 4; ++fn)
                acc[fm][fn] = __builtin_amdgcn_mfma_f32_16x16x32_bf16(af[fm], bf[fn], acc[fm][fn], 0, 0, 0);
        __syncthreads();
    }
    // epilogue: bias + cvt into LDS tile, then fully-coalesced 16B row-chunk writes
    #pragma unroll
    for (int fn = 0; fn < 4; ++fn) {
        int colg = n0 + wn * 64 + fn * 16 + mr;
        float bias = (colg < NCLS) ? bo[colg] : 0.f;
        #pragma unroll
        for (int fm = 0; fm < 4; ++fm)
            #pragma unroll
            for (int r = 0; r < 4; ++r)
                sC[wm * 64 + fm * 16 + g * 4 + r][wn * 64 + fn * 16 + mr] = f2b(acc[fm][fn][r] + bias);
    }
    __syncthreads();
    #pragma unroll
    for (int rr = 0; rr < 8; ++rr) {
        int row_l = (tid >> 4) + rr * 16;
        int col0 = (tid & 15) * 8;
        int gcol = n0 + col0;
        if (gcol < NCLS)   // NCLS % 8 == 0 -> whole chunk valid iff start valid
            *(int4*)&Cb[(size_t)(m0 + row_l) * NCLS + gcol] = *(int4*)&sC[row_l][col0];
    }
}

// ---- logits GEMM, f32 C (fallback path) ----------------------------------
__launch_bounds__(256)
__global__ void gemm_logits_mfma(const unsigned short* __restrict__ A,
                                 const unsigned short* __restrict__ Bt,
                                 const float* __restrict__ bo,
                                 float* __restrict__ C) {
    __shared__ unsigned short As[128 * 32];
    __shared__ unsigned short Bs[128 * 32];
    const int tid = threadIdx.x;
    const int wave = tid >> 6, lane = tid & 63;
    const int wm = wave >> 1, wn = wave & 1;
    const int m0 = blockIdx.y * 128, n0 = blockIdx.x * 128;
    const int g = lane >> 4, mr = lane & 15;

    const int ch0 = wave * 64 + lane;
    const int ch1 = (4 + wave) * 64 + lane;
    const int row0 = ch0 >> 2, q0 = ch0 & 3;
    const int row1 = ch1 >> 2, q1 = ch1 & 3;

    f32x4 acc[4][4] = {};
    for (int kt = 0; kt < DSTATE; kt += 32) {
        __builtin_amdgcn_global_load_lds(
            (const __attribute__((address_space(1))) void*)&A[(size_t)(m0 + row0) * DSTATE + kt + q0 * 8],
            (__attribute__((address_space(3))) void*)&As[ch0 * 8 - lane * 8], 16, 0, 0);
        __builtin_amdgcn_global_load_lds(
            (const __attribute__((address_space(1))) void*)&A[(size_t)(m0 + row1) * DSTATE + kt + q1 * 8],
            (__attribute__((address_space(3))) void*)&As[ch1 * 8 - lane * 8], 16, 0, 0);
        __builtin_amdgcn_global_load_lds(
            (const __attribute__((address_space(1))) void*)&Bt[(size_t)(n0 + row0) * DSTATE + kt + q0 * 8],
            (__attribute__((address_space(3))) void*)&Bs[ch0 * 8 - lane * 8], 16, 0, 0);
        __builtin_amdgcn_global_load_lds(
            (const __attribute__((address_space(1))) void*)&Bt[(size_t)(n0 + row1) * DSTATE + kt + q1 * 8],
            (__attribute__((address_space(3))) void*)&Bs[ch1 * 8 - lane * 8], 16, 0, 0);
        __syncthreads();

        bf16x8 af[4], bf[4];
        #pragma unroll
        for (int f = 0; f < 4; ++f) {
            af[f] = *(const bf16x8*)&As[(wm * 64 + f * 16 + mr) * 32 + g * 8];
            bf[f] = *(const bf16x8*)&Bs[(wn * 64 + f * 16 + mr) * 32 + g * 8];
        }
        #pragma unroll
        for (int fm = 0; fm < 4; ++fm)
            #pragma unroll
            for (int fn = 0; fn < 4; ++fn)
                acc[fm][fn] = __builtin_amdgcn_mfma_f32_16x16x32_bf16(af[fm], bf[fn], acc[fm][fn], 0, 0, 0);
        __syncthreads();
    }
    #pragma unroll
    for (int fm = 0; fm < 4; ++fm) {
        #pragma unroll
        for (int fn = 0; fn < 4; ++fn) {
            int col = n0 + wn * 64 + fn * 16 + mr;
            if (col >= NCLS) continue;
            float bias = bo[col];
            #pragma unroll
            for (int r = 0; r < 4; ++r) {
                int row = m0 + wm * 64 + fm * 16 + g * 4 + r;
                C[(size_t)row * NCLS + col] = acc[fm][fn][r] + bias;
            }
        }
    }
}

// ---- softmax + loss ------------------------------------------------------
__device__ inline float wave_reduce_max(float v) {
    #pragma unroll
    for (int off = 32; off > 0; off >>= 1) v = fmaxf(v, __shfl_xor(v, off));
    return v;
}
__device__ inline float wave_reduce_sum(float v) {
    #pragma unroll
    for (int off = 32; off > 0; off >>= 1) v += __shfl_xor(v, off);
    return v;
}

// bf16-input softmax, 512 threads (8 waves) for full occupancy at 40KB LDS.
__launch_bounds__(512)
__global__ void softmax_loss_bf16(const unsigned short* __restrict__ Cb,  // [chunk][NCLS]
                                  const float* __restrict__ labels,       // chunk base
                                  float* __restrict__ probs,              // chunk base
                                  float* __restrict__ rowloss) {          // chunk base
    __shared__ float row[NCLS];          // 40 KB
    __shared__ float sm[8];
    const int tid = threadIdx.x;
    const size_t base = (size_t)blockIdx.x * NCLS;

    float m = -INFINITY;
    for (int c8 = tid; c8 < NCLS / 8; c8 += 512) {
        ushort4 u0 = *(const ushort4*)&Cb[base + c8 * 8];
        ushort4 u1 = *(const ushort4*)&Cb[base + c8 * 8 + 4];
        float v0 = b2f(u0.x), v1 = b2f(u0.y), v2 = b2f(u0.z), v3 = b2f(u0.w);
        float v4 = b2f(u1.x), v5 = b2f(u1.y), v6 = b2f(u1.z), v7 = b2f(u1.w);
        float4 a = {v0, v1, v2, v3}, b = {v4, v5, v6, v7};
        *(float4*)&row[c8 * 8] = a;
        *(float4*)&row[c8 * 8 + 4] = b;
        m = fmaxf(m, fmaxf(fmaxf(fmaxf(v0, v1), fmaxf(v2, v3)),
                           fmaxf(fmaxf(v4, v5), fmaxf(v6, v7))));
    }
    m = wave_reduce_max(m);
    if ((tid & 63) == 0) sm[tid >> 6] = m;
    __syncthreads();
    m = fmaxf(fmaxf(fmaxf(sm[0], sm[1]), fmaxf(sm[2], sm[3])),
              fmaxf(fmaxf(sm[4], sm[5]), fmaxf(sm[6], sm[7])));
    __syncthreads();

    float s = 0.f, dot = 0.f;
    for (int c4 = tid; c4 < NCLS / 4; c4 += 512) {
        float4 v = *(const float4*)&row[c4 * 4];
        float4 lb = *(const float4*)&labels[base + c4 * 4];
        s += expf(v.x - m) + expf(v.y - m) + expf(v.z - m) + expf(v.w - m);
        dot += lb.x * v.x + lb.y * v.y + lb.z * v.z + lb.w * v.w;
    }
    s = wave_reduce_sum(s);
    if ((tid & 63) == 0) sm[tid >> 6] = s;
    __syncthreads();
    s = ((sm[0] + sm[1]) + (sm[2] + sm[3])) + ((sm[4] + sm[5]) + (sm[6] + sm[7]));
    __syncthreads();
    dot = wave_reduce_sum(dot);
    if ((tid & 63) == 0) sm[tid >> 6] = dot;
    __syncthreads();
    dot = ((sm[0] + sm[1]) + (sm[2] + sm[3])) + ((sm[4] + sm[5]) + (sm[6] + sm[7]));

    float inv = 1.f / s;
    for (int c4 = tid; c4 < NCLS / 4; c4 += 512) {
        float4 v = *(const float4*)&row[c4 * 4];
        float4 o;
        o.x = expf(v.x - m) * inv; o.y = expf(v.y - m) * inv;
        o.z = expf(v.z - m) * inv; o.w = expf(v.w - m) * inv;
        *(float4*)&probs[base + c4 * 4] = o;
    }
    if (tid == 0) rowloss[blockIdx.x] = (m + logf(s)) - dot;
}

// f32 in-place softmax (fallback path)
__launch_bounds__(256)
__global__ void softmax_loss(float* __restrict__ logits,
                             const float* __restrict__ labels,
                             float* __restrict__ rowloss) {
    __shared__ float row[NCLS];
    __shared__ float sm[4];
    const int tid = threadIdx.x;
    const size_t base = (size_t)blockIdx.x * NCLS;

    float m = -INFINITY;
    for (int c4 = tid; c4 < NCLS / 4; c4 += 256) {
        float4 v = *(const float4*)&logits[base + c4 * 4];
        *(float4*)&row[c4 * 4] = v;
        m = fmaxf(fmaxf(m, fmaxf(v.x, v.y)), fmaxf(v.z, v.w));
    }
    m = wave_reduce_max(m);
    if ((tid & 63) == 0) sm[tid >> 6] = m;
    __syncthreads();
    m = fmaxf(fmaxf(sm[0], sm[1]), fmaxf(sm[2], sm[3]));
    __syncthreads();

    float s = 0.f, dot = 0.f;
    for (int c4 = tid; c4 < NCLS / 4; c4 += 256) {
        float4 v = *(const float4*)&row[c4 * 4];
        float4 lb = *(const float4*)&labels[base + c4 * 4];
        s += expf(v.x - m) + expf(v.y - m) + expf(v.z - m) + expf(v.w - m);
        dot += lb.x * v.x + lb.y * v.y + lb.z * v.z + lb.w * v.w;
    }
    s = wave_reduce_sum(s);
    if ((tid & 63) == 0) sm[tid >> 6] = s;
    __syncthreads();
    s = sm[0] + sm[1] + sm[2] + sm[3];
    __syncthreads();
    dot = wave_reduce_sum(dot);
    if ((tid & 63) == 0) sm[tid >> 6] = dot;
    __syncthreads();
    dot = sm[0] + sm[1] + sm[2] + sm[3];

    float inv = 1.f / s;
    for (int c4 = tid; c4 < NCLS / 4; c4 += 256) {
        float4 v = *(const float4*)&row[c4 * 4];
        float4 o;
        o.x = expf(v.x - m) * inv; o.y = expf(v.y - m) * inv;
        o.z = expf(v.z - m) * inv; o.w = expf(v.w - m) * inv;
        *(float4*)&logits[base + c4 * 4] = o;
    }
    if (tid == 0) rowloss[blockIdx.x] = (m + logf(s)) - dot;
}

__launch_bounds__(256)
__global__ void loss_reduce(const float* __restrict__ rowloss, float* __restrict__ out) {
    __shared__ float sm[4];
    float s = 0.f;
    for (int i = threadIdx.x; i < ROWS; i += 256) s += rowloss[i];
    s = wave_reduce_sum(s);
    if ((threadIdx.x & 63) == 0) sm[threadIdx.x >> 6] = s;
    __syncthreads();
    if (threadIdx.x == 0) out[0] = (sm[0] + sm[1] + sm[2] + sm[3]) * (1.f / ROWS);
}

// ---- launcher ------------------------------------------------------------
extern "C" void kernel_launch(void* const* d_in, const int* in_sizes, int n_in,
                              void* d_out, int out_size, void* d_ws, size_t ws_size,
                              hipStream_t stream) {
    const float* inputs = (const float*)d_in[0];
    const float* labels = (const float*)d_in[1];
    const float* c0     = (const float*)d_in[2];   // initial_state (cell)
    const float* h0     = (const float*)d_in[3];   // initial_output (hidden)
    const float* Wx     = (const float*)d_in[4];
    const float* Wh     = (const float*)d_in[5];
    const float* bias   = (const float*)d_in[6];
    const float* Wo     = (const float*)d_in[7];
    const float* bo     = (const float*)d_in[8];
    float* out = (float*)d_out;

    float* ws = (float*)d_ws;
    float* bp       = ws;                                  // 2048 f32
    float* rowloss  = bp + 2048;                           // 16384 f32
    unsigned short* WhT = (unsigned short*)(rowloss + 16384); // 2048*512
    unsigned short* WxT = WhT + 1048576;                   // 2048*256
    unsigned short* Xb  = WxT + 524288;                    // 16384*256
    unsigned short* h0b = Xb + 4194304;                    // 64*512
    unsigned short* hsb = h0b + 32768;                     // 16384*512
    unsigned short* WoT = hsb + 8388608;                   // 10112*512
    unsigned short* ZxT = WoT + 5177344;                   // 256*2048*64
    unsigned* bar = (unsigned*)(ZxT + 33554432);           // 1024 words (4 grp x 16 flags x 16 stride)
    unsigned short* Cb = (unsigned short*)(bar + 1024);    // CHUNK_ROWS*NCLS bf16

    size_t base_bytes = (size_t)((char*)Cb - (char*)d_ws);
    size_t need_bf16 = base_bytes + (size_t)CHUNK_ROWS * NCLS * sizeof(unsigned short);
    bool use_bf16 = (ws_size >= need_bf16);

    prep_all<<<11548, 256, 0, stream>>>(inputs, Wx, Wh, bias, h0, Wo,
                                        Xb, WxT, WhT, bp, h0b, bar, WoT);

    zx_gemm<<<dim3(T_STEPS, NGATE / 128), 256, 0, stream>>>(Xb, WxT, bp, ZxT);

    void* args[] = {(void*)&h0b, (void*)&c0, (void*)&WhT, (void*)&ZxT, (void*)&hsb, (void*)&bar};
    hipLaunchCooperativeKernel((const void*)lstm_scan_mfma, dim3(SCAN_BLOCKS), dim3(256),
                               args, 0, stream);

    if (use_bf16) {
        for (int row0 = 0; row0 < ROWS; row0 += CHUNK_ROWS) {
            gemm_logits_bf16<<<dim3(NCLS_PAD / 128, CHUNK_ROWS / 128), 256, 0, stream>>>(
                hsb + (size_t)row0 * DSTATE, WoT, bo, Cb);
            softmax_loss_bf16<<<CHUNK_ROWS, 512, 0, stream>>>(
                Cb, labels + (size_t)row0 * NCLS, out + (size_t)row0 * NCLS, rowloss + row0);
        }
    } else {
        gemm_logits_mfma<<<dim3(NCLS_PAD / 128, ROWS / 128), 256, 0, stream>>>(hsb, WoT, bo, out);
        softmax_loss<<<ROWS, 256, 0, stream>>>(out, labels, rowloss);
    }
    loss_reduce<<<1, 256, 0, stream>>>(rowloss, out + (size_t)ROWS * NCLS);
}